// Round 15
// baseline (7354.754 us; speedup 1.0000x reference)
//
#include <hip/hip_runtime.h>
#include <hip/hip_cooperative_groups.h>
#include <math.h>

namespace cg = cooperative_groups;

// GRU rollout via MFMA 16x16x32 bf16.
// Fragment-major operands (1KB = 16 rows x 32 k per block); coalesced 1KB loads.
// Fast path: ONE persistent cooperative kernel runs all gate steps
// (512 wgs x 256 thr = 2/CU co-resident; tile 128x64; XCD blocking 4mt x 16nt;
// single-pass ah*bh; grid.sync() between steps) -> kills 99x dispatch overhead.
// h_hi history -> one batched PROJ GEMM at the end (hi-only B).
// Fallbacks: per-step k_gates loop (if coop launch fails); R8 fused (small ws).

#define B_SZ 2048
#define LAT  256
#define HID  512
#define NROW 2304
#define HN   (B_SZ * HID)

typedef unsigned short u16;
typedef __attribute__((ext_vector_type(8))) short s16x8;
typedef __attribute__((ext_vector_type(4))) float f32x4;

__device__ __forceinline__ float sigm(float x) { return 1.0f / (1.0f + __expf(-x)); }
__device__ __forceinline__ float tanh_f(float x) {
    float e = __expf(-2.0f * fabsf(x));
    float t = (1.0f - e) / (1.0f + e);
    return copysignf(t, x);
}
__device__ __forceinline__ u16 f2bf(float x) {
    unsigned u = __float_as_uint(x);
    return (u16)((u + 0x7FFFu + ((u >> 16) & 1u)) >> 16);
}
__device__ __forceinline__ float bf2f(u16 h) { return __uint_as_float((unsigned)h << 16); }

// fragment-major short-offset for element (row n, k)
__device__ __forceinline__ size_t fidx(int n, int k) {
    return ((size_t)(n >> 4) * 16 + (k >> 5)) * 512 +
           (size_t)((k >> 3) & 3) * 128 + (n & 15) * 8 + (k & 7);
}

// ---------------- Bias[512][12] ----------------
__global__ __launch_bounds__(64) void k_bias(
    const float* __restrict__ W_ih, const float* __restrict__ b_ih,
    const float* __restrict__ b_hh, const float* __restrict__ b_pr,
    float* __restrict__ Bias)
{
    const int u = blockIdx.x;
    const int t = threadIdx.x;
    float dr = 0.f, dz = 0.f, dn = 0.f;
    for (int o = t; o < 256; o += 64) {
        float bo = b_pr[o];
        dr = fmaf(bo, W_ih[(size_t)u * 258 + o], dr);
        dz = fmaf(bo, W_ih[(size_t)(HID + u) * 258 + o], dz);
        dn = fmaf(bo, W_ih[(size_t)(2 * HID + u) * 258 + o], dn);
    }
    #pragma unroll
    for (int off = 32; off > 0; off >>= 1) {
        dr += __shfl_down(dr, off);
        dz += __shfl_down(dz, off);
        dn += __shfl_down(dn, off);
    }
    if (t == 0) {
        float* b = Bias + u * 12;
        b[0]  = b_ih[u] + b_hh[u] + dr;
        b[1]  = W_ih[(size_t)u * 258 + 256];
        b[2]  = W_ih[(size_t)u * 258 + 257];
        b[3]  = b_ih[HID + u] + b_hh[HID + u] + dz;
        b[4]  = W_ih[(size_t)(HID + u) * 258 + 256];
        b[5]  = W_ih[(size_t)(HID + u) * 258 + 257];
        b[6]  = b_ih[2 * HID + u] + dn;
        b[7]  = W_ih[(size_t)(2 * HID + u) * 258 + 256];
        b[8]  = W_ih[(size_t)(2 * HID + u) * 258 + 257];
        b[9]  = b_hh[2 * HID + u];
        b[10] = b_hh[u];
        b[11] = b_hh[HID + u];
    }
}

// ---------------- gi1_T[1536][2048] = x1 @ Wih^T + b_ih; out[0] = p0 ----------------
__global__ __launch_bounds__(512) void k_gi1(
    const float* __restrict__ p0, const float* __restrict__ latv,
    const float* __restrict__ lonv, const float* __restrict__ W_ih,
    const float* __restrict__ b_ih, float* __restrict__ gi1T,
    float* __restrict__ out)
{
    const int rb = blockIdx.x;
    const int t  = threadIdx.x;
    __shared__ float p0s[8][256];
    __shared__ float lat_s[8], lon_s[8];
    for (int i = t; i < 8 * 256; i += 512) {
        int r = i >> 8, o = i & 255;
        float v = p0[(size_t)(rb * 8 + r) * LAT + o];
        p0s[r][o] = v;
        out[(size_t)(rb * 8 + r) * LAT + o] = v;
    }
    if (t < 8) { lat_s[t] = latv[rb * 8 + t]; lon_s[t] = lonv[rb * 8 + t]; }
    __syncthreads();

    for (int gg = 0; gg < 3; ++gg) {
        const int grow = t + gg * 512;
        const float* wr = W_ih + (size_t)grow * 258;
        float acc[8];
        float bi = b_ih[grow];
        #pragma unroll
        for (int r = 0; r < 8; ++r) acc[r] = bi;
        for (int o = 0; o < 256; ++o) {
            float wv = wr[o];
            #pragma unroll
            for (int r = 0; r < 8; ++r) acc[r] = fmaf(wv, p0s[r][o], acc[r]);
        }
        float c1 = wr[256], c2 = wr[257];
        #pragma unroll
        for (int r = 0; r < 8; ++r) {
            acc[r] = fmaf(lat_s[r], c1, acc[r]);
            acc[r] = fmaf(lon_s[r], c2, acc[r]);
            gi1T[(size_t)grow * B_SZ + rb * 8 + r] = acc[r];
        }
    }
}

// ---------------- h_1 (h0 = 0) -> slab 1 of Hhi and Hlo ----------------
__global__ __launch_bounds__(256) void k_h1(
    const float* __restrict__ gi1T, const float* __restrict__ Bias,
    u16* __restrict__ Hhi, u16* __restrict__ Hlo)
{
    const int idx = blockIdx.x * 256 + threadIdx.x;
    const int row = idx & (B_SZ - 1);
    const int u   = idx >> 11;
    const float* bb = Bias + (size_t)u * 12;
    float r = sigm(gi1T[(size_t)u * B_SZ + row] + bb[10]);
    float z = sigm(gi1T[(size_t)(HID + u) * B_SZ + row] + bb[11]);
    float n = tanh_f(fmaf(r, bb[9], gi1T[(size_t)(2 * HID + u) * B_SZ + row]));
    float h = n - z * n;
    u16 hi = f2bf(h);
    size_t off = HN + fidx(row, u);
    Hhi[off] = hi;
    Hlo[off] = f2bf(h - bf2f(hi));
}

// ---------------- Wcat (2304 x 512) fused + split, fragment-major ----------------
__global__ __launch_bounds__(512) void k_wsplit(
    const float* __restrict__ W_ih, const float* __restrict__ W_hh,
    const float* __restrict__ W_pr, u16* __restrict__ Whi, u16* __restrict__ Wlo)
{
    const int n = blockIdx.x;
    const int k = threadIdx.x;
    const int u = n >> 2, g = n & 3;
    __shared__ float wr[256];
    if (n < 2048 && g != 3 && k < 256)
        wr[k] = W_ih[(size_t)(g * HID + u) * 258 + k];
    __syncthreads();

    float w;
    if (n >= 2048) {
        w = W_pr[(size_t)(n - 2048) * HID + k];
    } else if (g == 3) {
        w = W_hh[(size_t)(2 * HID + u) * HID + k];
    } else {
        float acc = 0.f;
        for (int o = 0; o < 256; ++o)
            acc = fmaf(wr[o], W_pr[(size_t)o * HID + k], acc);
        if (g == 0)      acc += W_hh[(size_t)u * HID + k];
        else if (g == 1) acc += W_hh[(size_t)(HID + u) * HID + k];
        w = acc;
    }
    u16 hi = f2bf(w);
    size_t off = fidx(n, k);
    Whi[off] = hi;
    Wlo[off] = f2bf(w - bf2f(hi));
}

// ---------------- FAST PATH: persistent cooperative gates kernel ----------------
// 512 wgs x 256 thr (2/CU co-resident). Per step: tile 128(M) x 64(N), K=512,
// XCD blocking 4mt x 16nt, single-pass ah*bh. grid.sync() between steps.
__global__ __launch_bounds__(256, 2) void k_gates_all(
    u16* __restrict__ Hhi, u16* __restrict__ Hlo,
    const u16* __restrict__ Whi,
    const float* __restrict__ Bias,
    const float* __restrict__ latv, const float* __restrict__ lonv,
    int NS)
{
    cg::grid_group grid = cg::this_grid();

    const int bid = blockIdx.x;
    const int xcd = bid & 7, loc = bid >> 3;        // 64 wgs per XCD
    const int mt  = (xcd & 3) * 4 + (loc & 3);      // 0..15 (128-row panels)
    const int nt  = (xcd >> 2) * 16 + (loc >> 2);   // 0..31 (64-col panels)
    const int m0  = mt * 128, n0 = nt * 64;
    const int t    = threadIdx.x;
    const int lane = t & 63, wave = t >> 6;
    const int wm   = wave >> 1, wn = wave & 1;      // 2x2 waves, wave-tile 64x32
    const int q    = lane >> 4, c = lane & 15;

    __shared__ float Gt[128][68];                   // 34.8 KB
    __shared__ float bias_s[16][12];
    if (t < 192) ((float*)bias_s)[t] = Bias[(size_t)(n0 >> 2) * 12 + t];

    int aoff[4], boff[2];
    #pragma unroll
    for (int i = 0; i < 4; ++i)
        aoff[i] = ((mt * 8 + wm * 4 + i) * 16) * 512 + lane * 8;
    #pragma unroll
    for (int j = 0; j < 2; ++j)
        boff[j] = ((nt * 4 + wn * 2 + j) * 16) * 512 + lane * 8;

    // epilogue constants
    const int uo = t & 1;            // 8-unit group within 16-unit tile
    const int ml = t >> 1;           // row 0..127
    const int m  = m0 + ml;
    const float lt = latv[m], ln = lonv[m];
    const size_t hoff = ((size_t)(m >> 4) * 16 + (nt >> 1)) * 512 +
                        (size_t)(((nt & 1) * 2 + uo)) * 128 + (m & 15) * 8;

    for (int s = 2; s <= NS; ++s) {
        if (s > 2) grid.sync();      // prev step's H writes visible, Gt free

        const u16* __restrict__ Hh = Hhi + (size_t)(s - 1) * HN;
        const u16* __restrict__ Hl = Hlo + (size_t)((s - 1) & 1) * HN;
        u16* __restrict__ Hhn = Hhi + (size_t)s * HN;
        u16* __restrict__ Hln = Hlo + (size_t)(s & 1) * HN;

        f32x4 acc[4][2];
        #pragma unroll
        for (int i = 0; i < 4; ++i)
            #pragma unroll
            for (int j = 0; j < 2; ++j) acc[i][j] = (f32x4){0.f, 0.f, 0.f, 0.f};

        #pragma unroll 2
        for (int kb = 0; kb < 16; ++kb) {
            const int ko = kb * 512;
            s16x8 ah[4], bh[2];
            #pragma unroll
            for (int i = 0; i < 4; ++i)
                ah[i] = *(const s16x8*)(Hh + aoff[i] + ko);
            #pragma unroll
            for (int j = 0; j < 2; ++j)
                bh[j] = *(const s16x8*)(Whi + boff[j] + ko);
            #pragma unroll
            for (int i = 0; i < 4; ++i)
                #pragma unroll
                for (int j = 0; j < 2; ++j)
                    acc[i][j] = __builtin_amdgcn_mfma_f32_16x16x32_bf16(ah[i], bh[j], acc[i][j], 0, 0, 0);
        }

        #pragma unroll
        for (int i = 0; i < 4; ++i)
            #pragma unroll
            for (int j = 0; j < 2; ++j)
                #pragma unroll
                for (int r = 0; r < 4; ++r)
                    Gt[wm * 64 + i * 16 + 4 * q + r][wn * 32 + j * 16 + c] = acc[i][j][r];
        __syncthreads();

        s16x8 hh8 = *(const s16x8*)(Hh + hoff);
        s16x8 hl8 = *(const s16x8*)(Hl + hoff);
        s16x8 vh, vl;
        #pragma unroll
        for (int j = 0; j < 8; ++j) {
            const float* bb = bias_s[uo * 8 + j];
            f32x4 gv = *(const f32x4*)&Gt[ml][(uo * 8 + j) * 4];
            float r = sigm(gv.x + bb[0] + lt * bb[1] + ln * bb[2]);
            float z = sigm(gv.y + bb[3] + lt * bb[4] + ln * bb[5]);
            float n = tanh_f(fmaf(r, gv.w + bb[9], gv.z + bb[6] + lt * bb[7] + ln * bb[8]));
            float hold = bf2f((u16)hh8[j]) + bf2f((u16)hl8[j]);
            float h = n + z * (hold - n);
            u16 hi = f2bf(h);
            vh[j] = (short)hi;
            vl[j] = (short)f2bf(h - bf2f(hi));
        }
        *(s16x8*)(Hhn + hoff) = vh;
        *(s16x8*)(Hln + hoff) = vl;
    }
}

// ---------------- FALLBACK fast path: per-step gates kernel (R14) ----------------
__global__ __launch_bounds__(256, 2) void k_gates(
    u16* __restrict__ Hhi, u16* __restrict__ Hlo,
    const u16* __restrict__ Whi,
    const float* __restrict__ Bias,
    const float* __restrict__ latv, const float* __restrict__ lonv,
    int sA, int sW, int ra, int rw)
{
    const int bid = blockIdx.x;
    const int xcd = bid & 7, loc = bid >> 3;
    const int mt  = (xcd & 3) * 4 + (loc & 3);
    const int nt  = (xcd >> 2) * 16 + (loc >> 2);
    const int m0  = mt * 128, n0 = nt * 64;
    const int t    = threadIdx.x;
    const int lane = t & 63, wave = t >> 6;
    const int wm   = wave >> 1, wn = wave & 1;
    const int q    = lane >> 4, c = lane & 15;

    __shared__ float Gt[128][68];
    __shared__ float bias_s[16][12];
    if (t < 192) ((float*)bias_s)[t] = Bias[(size_t)(n0 >> 2) * 12 + t];

    const u16* __restrict__ Hh = Hhi + (size_t)sA * HN;
    const u16* __restrict__ Hl = Hlo + (size_t)ra * HN;

    int aoff[4], boff[2];
    #pragma unroll
    for (int i = 0; i < 4; ++i)
        aoff[i] = ((mt * 8 + wm * 4 + i) * 16) * 512 + lane * 8;
    #pragma unroll
    for (int j = 0; j < 2; ++j)
        boff[j] = ((nt * 4 + wn * 2 + j) * 16) * 512 + lane * 8;

    f32x4 acc[4][2];
    #pragma unroll
    for (int i = 0; i < 4; ++i)
        #pragma unroll
        for (int j = 0; j < 2; ++j) acc[i][j] = (f32x4){0.f, 0.f, 0.f, 0.f};

    #pragma unroll 2
    for (int kb = 0; kb < 16; ++kb) {
        const int ko = kb * 512;
        s16x8 ah[4], bh[2];
        #pragma unroll
        for (int i = 0; i < 4; ++i)
            ah[i] = *(const s16x8*)(Hh + aoff[i] + ko);
        #pragma unroll
        for (int j = 0; j < 2; ++j)
            bh[j] = *(const s16x8*)(Whi + boff[j] + ko);
        #pragma unroll
        for (int i = 0; i < 4; ++i)
            #pragma unroll
            for (int j = 0; j < 2; ++j)
                acc[i][j] = __builtin_amdgcn_mfma_f32_16x16x32_bf16(ah[i], bh[j], acc[i][j], 0, 0, 0);
    }

    #pragma unroll
    for (int i = 0; i < 4; ++i)
        #pragma unroll
        for (int j = 0; j < 2; ++j)
            #pragma unroll
            for (int r = 0; r < 4; ++r)
                Gt[wm * 64 + i * 16 + 4 * q + r][wn * 32 + j * 16 + c] = acc[i][j][r];
    __syncthreads();

    u16* __restrict__ Hhn = Hhi + (size_t)sW * HN;
    u16* __restrict__ Hln = Hlo + (size_t)rw * HN;

    const int uo = t & 1;
    const int ml = t >> 1;
    const int m  = m0 + ml;
    const float lt = latv[m], ln = lonv[m];
    const size_t hoff = ((size_t)(m >> 4) * 16 + (nt >> 1)) * 512 +
                        (size_t)(((nt & 1) * 2 + uo)) * 128 + (m & 15) * 8;
    s16x8 hh8 = *(const s16x8*)(Hh + hoff);
    s16x8 hl8 = *(const s16x8*)(Hl + hoff);
    s16x8 vh, vl;
    #pragma unroll
    for (int j = 0; j < 8; ++j) {
        const float* bb = bias_s[uo * 8 + j];
        f32x4 gv = *(const f32x4*)&Gt[ml][(uo * 8 + j) * 4];
        float r = sigm(gv.x + bb[0] + lt * bb[1] + ln * bb[2]);
        float z = sigm(gv.y + bb[3] + lt * bb[4] + ln * bb[5]);
        float n = tanh_f(fmaf(r, gv.w + bb[9], gv.z + bb[6] + lt * bb[7] + ln * bb[8]));
        float hold = bf2f((u16)hh8[j]) + bf2f((u16)hl8[j]);
        float h = n + z * (hold - n);
        u16 hi = f2bf(h);
        vh[j] = (short)hi;
        vl[j] = (short)f2bf(h - bf2f(hi));
    }
    *(s16x8*)(Hhn + hoff) = vh;
    *(s16x8*)(Hln + hoff) = vl;
}

// ---------------- FAST PATH: batched projection over all steps ----------------
__global__ __launch_bounds__(256, 2) void k_proj(
    const u16* __restrict__ Hhi, const u16* __restrict__ Whi,
    const float* __restrict__ b_pr, float* __restrict__ out)
{
    const int bid  = blockIdx.x;
    const int pt   = bid >> 1, ntp = bid & 1;
    const int slab = (pt >> 4) + 1;
    const int mt   = pt & 15;
    const int m0   = mt * 128;
    const int t    = threadIdx.x;
    const int lane = t & 63, wave = t >> 6;
    const int wm   = wave >> 1, wn = wave & 1;
    const int q    = lane >> 4, c = lane & 15;

    __shared__ float Gt[64][132];

    const u16* __restrict__ Hh = Hhi + (size_t)slab * HN;

    int aoff[4], boff[4];
    #pragma unroll
    for (int i = 0; i < 4; ++i) {
        aoff[i] = ((mt * 8 + wm * 4 + i) * 16) * 512 + lane * 8;
        boff[i] = ((128 + ntp * 8 + wn * 4 + i) * 16) * 512 + lane * 8;
    }

    f32x4 acc[4][4];
    #pragma unroll
    for (int i = 0; i < 4; ++i)
        #pragma unroll
        for (int j = 0; j < 4; ++j) acc[i][j] = (f32x4){0.f, 0.f, 0.f, 0.f};

    #pragma unroll 2
    for (int kb = 0; kb < 16; ++kb) {
        const int ko = kb * 512;
        s16x8 ah[4], bh[4];
        #pragma unroll
        for (int i = 0; i < 4; ++i) {
            ah[i] = *(const s16x8*)(Hh  + aoff[i] + ko);
            bh[i] = *(const s16x8*)(Whi + boff[i] + ko);
        }
        #pragma unroll
        for (int i = 0; i < 4; ++i)
            #pragma unroll
            for (int j = 0; j < 4; ++j)
                acc[i][j] = __builtin_amdgcn_mfma_f32_16x16x32_bf16(ah[i], bh[j], acc[i][j], 0, 0, 0);
    }

    for (int half = 0; half < 2; ++half) {
        __syncthreads();
        if (wm == half) {
            #pragma unroll
            for (int i = 0; i < 4; ++i)
                #pragma unroll
                for (int j = 0; j < 4; ++j)
                    #pragma unroll
                    for (int r = 0; r < 4; ++r)
                        Gt[i * 16 + 4 * q + r][wn * 64 + j * 16 + c] = acc[i][j][r];
        }
        __syncthreads();

        const int cl = t & 31, rg = t >> 5;
        const int o  = ntp * 128 + cl * 4;
        const float4 bp = *(const float4*)(b_pr + o);
        float* ob = out + (size_t)slab * B_SZ * LAT + o;
        #pragma unroll
        for (int i = 0; i < 8; ++i) {
            const int ml2 = rg * 8 + i;
            f32x4 g = *(const f32x4*)&Gt[ml2][cl * 4];
            *(float4*)(ob + (size_t)(m0 + half * 64 + ml2) * LAT) =
                make_float4(g.x + bp.x, g.y + bp.y, g.z + bp.z, g.w + bp.w);
        }
    }
}

// ---------------- FALLBACK (R8): fused per-step 128x128 GEMM (3-pass) ----------------
__global__ __launch_bounds__(256) void k_gemm(
    u16* __restrict__ Hhi, u16* __restrict__ Hlo,
    const u16* __restrict__ Whi, const u16* __restrict__ Wlo,
    const float* __restrict__ Bias, const float* __restrict__ b_pr,
    const float* __restrict__ latv, const float* __restrict__ lonv,
    float* __restrict__ out, int s, int ns, int ntb, int ntc)
{
    const int bid  = blockIdx.x;
    const int nt   = ntb + bid % ntc;
    const int mt   = bid / ntc;
    const int m0   = mt * 128, n0 = nt * 128;
    const int t    = threadIdx.x;
    const int lane = t & 63, wave = t >> 6;
    const int wm   = wave >> 1, wn = wave & 1;
    const int q    = lane >> 4, c = lane & 15;

    __shared__ float Gt[64][132];
    __shared__ float bias_s[32][12];
    if (n0 < 2048) {
        for (int i = t; i < 384; i += 256)
            ((float*)bias_s)[i] = Bias[(size_t)(n0 >> 2) * 12 + i];
    }

    const u16* __restrict__ Hh = Hhi + (size_t)((s - 1) & 1) * HN;
    const u16* __restrict__ Hl = Hlo + (size_t)((s - 1) & 1) * HN;

    int aoff[4], boff[4];
    #pragma unroll
    for (int i = 0; i < 4; ++i) {
        aoff[i] = ((mt * 8 + wm * 4 + i) * 16) * 512 + lane * 8;
        boff[i] = ((nt * 8 + wn * 4 + i) * 16) * 512 + lane * 8;
    }

    f32x4 acc[4][4];
    #pragma unroll
    for (int i = 0; i < 4; ++i)
        #pragma unroll
        for (int j = 0; j < 4; ++j) acc[i][j] = (f32x4){0.f, 0.f, 0.f, 0.f};

    #pragma unroll 2
    for (int kb = 0; kb < 16; ++kb) {
        const int ko = kb * 512;
        s16x8 ah[4], al[4], bh[4], bl[4];
        #pragma unroll
        for (int i = 0; i < 4; ++i) {
            ah[i] = *(const s16x8*)(Hh  + aoff[i] + ko);
            al[i] = *(const s16x8*)(Hl  + aoff[i] + ko);
            bh[i] = *(const s16x8*)(Whi + boff[i] + ko);
            bl[i] = *(const s16x8*)(Wlo + boff[i] + ko);
        }
        #pragma unroll
        for (int i = 0; i < 4; ++i)
            #pragma unroll
            for (int j = 0; j < 4; ++j) {
                acc[i][j] = __builtin_amdgcn_mfma_f32_16x16x32_bf16(ah[i], bh[j], acc[i][j], 0, 0, 0);
                acc[i][j] = __builtin_amdgcn_mfma_f32_16x16x32_bf16(al[i], bh[j], acc[i][j], 0, 0, 0);
                acc[i][j] = __builtin_amdgcn_mfma_f32_16x16x32_bf16(ah[i], bl[j], acc[i][j], 0, 0, 0);
            }
    }

    u16* __restrict__ Hhn = Hhi + (size_t)(s & 1) * HN;
    u16* __restrict__ Hln = Hlo + (size_t)(s & 1) * HN;
    const int u0t = n0 >> 2;

    for (int half = 0; half < 2; ++half) {
        __syncthreads();
        if (wm == half) {
            #pragma unroll
            for (int i = 0; i < 4; ++i)
                #pragma unroll
                for (int j = 0; j < 4; ++j)
                    #pragma unroll
                    for (int r = 0; r < 4; ++r)
                        Gt[i * 16 + 4 * q + r][wn * 64 + j * 16 + c] = acc[i][j][r];
        }
        __syncthreads();

        if (n0 < 2048) {
            const int uo = t & 3;
            const int ml = t >> 2;
            const int m  = m0 + half * 64 + ml;
            const float lt = latv[m], ln = lonv[m];
            const size_t hoff = ((size_t)(m >> 4) * 16 + (u0t >> 5)) * 512 +
                                (size_t)uo * 128 + (m & 15) * 8;
            s16x8 hh8 = *(const s16x8*)(Hh + hoff);
            s16x8 hl8 = *(const s16x8*)(Hl + hoff);
            s16x8 vh, vl;
            #pragma unroll
            for (int j = 0; j < 8; ++j) {
                const float* bb = bias_s[uo * 8 + j];
                f32x4 gv = *(const f32x4*)&Gt[ml][(uo * 8 + j) * 4];
                float r = sigm(gv.x + bb[0] + lt * bb[1] + ln * bb[2]);
                float z = sigm(gv.y + bb[3] + lt * bb[4] + ln * bb[5]);
                float n = tanh_f(fmaf(r, gv.w + bb[9], gv.z + bb[6] + lt * bb[7] + ln * bb[8]));
                float hold = bf2f((u16)hh8[j]) + bf2f((u16)hl8[j]);
                float h = n + z * (hold - n);
                u16 hi = f2bf(h);
                vh[j] = (short)hi;
                vl[j] = (short)f2bf(h - bf2f(hi));
            }
            *(s16x8*)(Hhn + hoff) = vh;
            *(s16x8*)(Hln + hoff) = vl;
        } else {
            const int cl = t & 31, rg = t >> 5;
            const int o  = (n0 - 2048) + cl * 4;
            const float4 bp = *(const float4*)(b_pr + o);
            float* ob = out + (size_t)(s - 1) * B_SZ * LAT + o;
            #pragma unroll
            for (int i = 0; i < 8; ++i) {
                const int ml = rg * 8 + i;
                f32x4 g = *(const f32x4*)&Gt[ml][cl * 4];
                *(float4*)(ob + (size_t)(m0 + half * 64 + ml) * LAT) =
                    make_float4(g.x + bp.x, g.y + bp.y, g.z + bp.z, g.w + bp.w);
            }
        }
    }
}

extern "C" void kernel_launch(void* const* d_in, const int* in_sizes, int n_in,
                              void* d_out, int out_size, void* d_ws, size_t ws_size,
                              hipStream_t stream)
{
    const float* p0   = (const float*)d_in[0];
    const float* latv = (const float*)d_in[1];
    const float* lonv = (const float*)d_in[2];
    const float* W_ih = (const float*)d_in[3];
    const float* W_hh = (const float*)d_in[4];
    const float* b_ih = (const float*)d_in[5];
    const float* b_hh = (const float*)d_in[6];
    const float* W_pr = (const float*)d_in[7];
    const float* b_pr = (const float*)d_in[8];
    float* out = (float*)d_out;

    const int NS = out_size / (B_SZ * LAT) - 1;   // 100

    // layout: gi1T | Bias | Hhi[nslab] | Hlo[2]; Whi/Wlo alias gi1T (dead after k_h1)
    float* gi1T = (float*)d_ws;
    float* Bias = gi1T + 3 * HID * B_SZ;
    u16*   Whi  = (u16*)gi1T;
    u16*   Wlo  = Whi + (size_t)NROW * HID;

    const size_t offH     = ((size_t)3 * HID * B_SZ + 512 * 12) * sizeof(float);
    const size_t slabB    = (size_t)HN * sizeof(u16);
    const size_t needFast = offH + (size_t)(NS + 1) * slabB + 2 * slabB;
    const bool   fast     = ws_size >= needFast;
    const int    nslabHi  = fast ? (NS + 1) : 2;

    u16* Hhi = (u16*)((char*)d_ws + offH);
    u16* Hlo = Hhi + (size_t)nslabHi * HN;

    hipLaunchKernelGGL(k_bias,   dim3(HID),  dim3(64),  0, stream, W_ih, b_ih, b_hh, b_pr, Bias);
    hipLaunchKernelGGL(k_gi1,    dim3(256),  dim3(512), 0, stream, p0, latv, lonv, W_ih, b_ih, gi1T, out);
    hipLaunchKernelGGL(k_h1,     dim3(4096), dim3(256), 0, stream, gi1T, Bias, Hhi, Hlo);
    hipLaunchKernelGGL(k_wsplit, dim3(NROW), dim3(512), 0, stream, W_ih, W_hh, W_pr, Whi, Wlo);

    if (fast) {
        int ns_arg = NS;
        void* cargs[] = { (void*)&Hhi, (void*)&Hlo, (void*)&Whi, (void*)&Bias,
                          (void*)&latv, (void*)&lonv, (void*)&ns_arg };
        hipError_t ce = hipLaunchCooperativeKernel((const void*)k_gates_all,
                                                   dim3(512), dim3(256),
                                                   cargs, 0, stream);
        if (ce != hipSuccess) {
            (void)hipGetLastError();   // clear; fall back to per-step launches
            for (int s = 2; s <= NS; ++s) {
                hipLaunchKernelGGL(k_gates, dim3(512), dim3(256), 0, stream,
                                   Hhi, Hlo, Whi, Bias, latv, lonv,
                                   s - 1, s, (s - 1) & 1, s & 1);
            }
        }
        hipLaunchKernelGGL(k_proj, dim3(NS * 32), dim3(256), 0, stream,
                           Hhi, Whi, b_pr, out);
    } else {
        for (int s = 2; s <= NS + 1; ++s) {
            const int ntc = (s <= NS) ? 18 : 2;
            const int ntb = (s <= NS) ? 0 : 16;
            hipLaunchKernelGGL(k_gemm, dim3(16 * ntc), dim3(256), 0, stream,
                               Hhi, Hlo, Whi, Wlo, Bias, b_pr, latv, lonv, out, s, NS, ntb, ntc);
        }
    }
}

// Round 16
// 1398.940 us; speedup vs baseline: 5.2574x; 5.2574x over previous
//
#include <hip/hip_runtime.h>
#include <math.h>

// GRU rollout via MFMA 16x16x32 bf16.
// Fragment-major operands (1KB = 16 rows x 32 k per block); coalesced 1KB loads.
// Fast path: per-step GATES-ONLY GEMM, tile 64x64, grid 1024 wgs x 256 thr
// = 4 wgs/CU = 4 waves/SIMD (max TLP for latency hiding). XCD blocking
// 8mt x 16nt (per-XCD set 1.5MB, L2-fit). Single-pass ah*bh.
// h_hi history -> one batched PROJ GEMM at the end (hi-only B).
// Fallback (small ws): R8 fused per-step kernel (3-pass, exact).

#define B_SZ 2048
#define LAT  256
#define HID  512
#define NROW 2304
#define HN   (B_SZ * HID)

typedef unsigned short u16;
typedef __attribute__((ext_vector_type(4))) short s16x4;
typedef __attribute__((ext_vector_type(8))) short s16x8;
typedef __attribute__((ext_vector_type(4))) float f32x4;

__device__ __forceinline__ float sigm(float x) { return 1.0f / (1.0f + __expf(-x)); }
__device__ __forceinline__ float tanh_f(float x) {
    float e = __expf(-2.0f * fabsf(x));
    float t = (1.0f - e) / (1.0f + e);
    return copysignf(t, x);
}
__device__ __forceinline__ u16 f2bf(float x) {
    unsigned u = __float_as_uint(x);
    return (u16)((u + 0x7FFFu + ((u >> 16) & 1u)) >> 16);
}
__device__ __forceinline__ float bf2f(u16 h) { return __uint_as_float((unsigned)h << 16); }

// fragment-major short-offset for element (row n, k)
__device__ __forceinline__ size_t fidx(int n, int k) {
    return ((size_t)(n >> 4) * 16 + (k >> 5)) * 512 +
           (size_t)((k >> 3) & 3) * 128 + (n & 15) * 8 + (k & 7);
}

// ---------------- Bias[512][12] ----------------
__global__ __launch_bounds__(64) void k_bias(
    const float* __restrict__ W_ih, const float* __restrict__ b_ih,
    const float* __restrict__ b_hh, const float* __restrict__ b_pr,
    float* __restrict__ Bias)
{
    const int u = blockIdx.x;
    const int t = threadIdx.x;
    float dr = 0.f, dz = 0.f, dn = 0.f;
    for (int o = t; o < 256; o += 64) {
        float bo = b_pr[o];
        dr = fmaf(bo, W_ih[(size_t)u * 258 + o], dr);
        dz = fmaf(bo, W_ih[(size_t)(HID + u) * 258 + o], dz);
        dn = fmaf(bo, W_ih[(size_t)(2 * HID + u) * 258 + o], dn);
    }
    #pragma unroll
    for (int off = 32; off > 0; off >>= 1) {
        dr += __shfl_down(dr, off);
        dz += __shfl_down(dz, off);
        dn += __shfl_down(dn, off);
    }
    if (t == 0) {
        float* b = Bias + u * 12;
        b[0]  = b_ih[u] + b_hh[u] + dr;
        b[1]  = W_ih[(size_t)u * 258 + 256];
        b[2]  = W_ih[(size_t)u * 258 + 257];
        b[3]  = b_ih[HID + u] + b_hh[HID + u] + dz;
        b[4]  = W_ih[(size_t)(HID + u) * 258 + 256];
        b[5]  = W_ih[(size_t)(HID + u) * 258 + 257];
        b[6]  = b_ih[2 * HID + u] + dn;
        b[7]  = W_ih[(size_t)(2 * HID + u) * 258 + 256];
        b[8]  = W_ih[(size_t)(2 * HID + u) * 258 + 257];
        b[9]  = b_hh[2 * HID + u];
        b[10] = b_hh[u];
        b[11] = b_hh[HID + u];
    }
}

// ---------------- gi1_T[1536][2048] = x1 @ Wih^T + b_ih; out[0] = p0 ----------------
__global__ __launch_bounds__(512) void k_gi1(
    const float* __restrict__ p0, const float* __restrict__ latv,
    const float* __restrict__ lonv, const float* __restrict__ W_ih,
    const float* __restrict__ b_ih, float* __restrict__ gi1T,
    float* __restrict__ out)
{
    const int rb = blockIdx.x;
    const int t  = threadIdx.x;
    __shared__ float p0s[8][256];
    __shared__ float lat_s[8], lon_s[8];
    for (int i = t; i < 8 * 256; i += 512) {
        int r = i >> 8, o = i & 255;
        float v = p0[(size_t)(rb * 8 + r) * LAT + o];
        p0s[r][o] = v;
        out[(size_t)(rb * 8 + r) * LAT + o] = v;
    }
    if (t < 8) { lat_s[t] = latv[rb * 8 + t]; lon_s[t] = lonv[rb * 8 + t]; }
    __syncthreads();

    for (int gg = 0; gg < 3; ++gg) {
        const int grow = t + gg * 512;
        const float* wr = W_ih + (size_t)grow * 258;
        float acc[8];
        float bi = b_ih[grow];
        #pragma unroll
        for (int r = 0; r < 8; ++r) acc[r] = bi;
        for (int o = 0; o < 256; ++o) {
            float wv = wr[o];
            #pragma unroll
            for (int r = 0; r < 8; ++r) acc[r] = fmaf(wv, p0s[r][o], acc[r]);
        }
        float c1 = wr[256], c2 = wr[257];
        #pragma unroll
        for (int r = 0; r < 8; ++r) {
            acc[r] = fmaf(lat_s[r], c1, acc[r]);
            acc[r] = fmaf(lon_s[r], c2, acc[r]);
            gi1T[(size_t)grow * B_SZ + rb * 8 + r] = acc[r];
        }
    }
}

// ---------------- h_1 (h0 = 0) -> slab 1 of Hhi and Hlo ----------------
__global__ __launch_bounds__(256) void k_h1(
    const float* __restrict__ gi1T, const float* __restrict__ Bias,
    u16* __restrict__ Hhi, u16* __restrict__ Hlo)
{
    const int idx = blockIdx.x * 256 + threadIdx.x;
    const int row = idx & (B_SZ - 1);
    const int u   = idx >> 11;
    const float* bb = Bias + (size_t)u * 12;
    float r = sigm(gi1T[(size_t)u * B_SZ + row] + bb[10]);
    float z = sigm(gi1T[(size_t)(HID + u) * B_SZ + row] + bb[11]);
    float n = tanh_f(fmaf(r, bb[9], gi1T[(size_t)(2 * HID + u) * B_SZ + row]));
    float h = n - z * n;
    u16 hi = f2bf(h);
    size_t off = HN + fidx(row, u);
    Hhi[off] = hi;
    Hlo[off] = f2bf(h - bf2f(hi));
}

// ---------------- Wcat (2304 x 512) fused + split, fragment-major ----------------
__global__ __launch_bounds__(512) void k_wsplit(
    const float* __restrict__ W_ih, const float* __restrict__ W_hh,
    const float* __restrict__ W_pr, u16* __restrict__ Whi, u16* __restrict__ Wlo)
{
    const int n = blockIdx.x;
    const int k = threadIdx.x;
    const int u = n >> 2, g = n & 3;
    __shared__ float wr[256];
    if (n < 2048 && g != 3 && k < 256)
        wr[k] = W_ih[(size_t)(g * HID + u) * 258 + k];
    __syncthreads();

    float w;
    if (n >= 2048) {
        w = W_pr[(size_t)(n - 2048) * HID + k];
    } else if (g == 3) {
        w = W_hh[(size_t)(2 * HID + u) * HID + k];
    } else {
        float acc = 0.f;
        for (int o = 0; o < 256; ++o)
            acc = fmaf(wr[o], W_pr[(size_t)o * HID + k], acc);
        if (g == 0)      acc += W_hh[(size_t)u * HID + k];
        else if (g == 1) acc += W_hh[(size_t)(HID + u) * HID + k];
        w = acc;
    }
    u16 hi = f2bf(w);
    size_t off = fidx(n, k);
    Whi[off] = hi;
    Wlo[off] = f2bf(w - bf2f(hi));
}

// ---------------- FAST PATH: gates-only step GEMM (2048x2048x512) ----------------
// Tile 64(M) x 64(N); grid 1024 wgs x 256 thr = 4 wgs/CU, 4 waves/SIMD.
// XCD blocking: xcd owns 8 mt x 16 nt -> per-XCD set = A 0.5MB + B 1MB (L2-fit).
// Single-pass ah*bh (h_lo/W_lo excluded from matmul; h state keeps hi+lo).
__global__ __launch_bounds__(256, 4) void k_gates(
    u16* __restrict__ Hhi, u16* __restrict__ Hlo,
    const u16* __restrict__ Whi,
    const float* __restrict__ Bias,
    const float* __restrict__ latv, const float* __restrict__ lonv,
    int sA, int sW, int ra, int rw)
{
    const int bid = blockIdx.x;
    const int xcd = bid & 7, loc = bid >> 3;        // 128 wgs per XCD
    const int mt  = (xcd & 3) * 8 + (loc & 7);      // 0..31 (64-row panels)
    const int nt  = (xcd >> 2) * 16 + (loc >> 3);   // 0..31 (64-col panels)
    const int m0  = mt * 64, n0 = nt * 64;
    const int t    = threadIdx.x;
    const int lane = t & 63, wave = t >> 6;
    const int wm   = wave >> 1, wn = wave & 1;      // 2x2 waves, wave-tile 32x32
    const int q    = lane >> 4, c = lane & 15;

    __shared__ float Gt[64][68];                    // 17.4 KB
    __shared__ float bias_s[16][12];
    if (t < 192) ((float*)bias_s)[t] = Bias[(size_t)(n0 >> 2) * 12 + t];

    const u16* __restrict__ Hh = Hhi + (size_t)sA * HN;
    const u16* __restrict__ Hl = Hlo + (size_t)ra * HN;

    int aoff[2], boff[2];
    #pragma unroll
    for (int i = 0; i < 2; ++i)
        aoff[i] = ((mt * 4 + wm * 2 + i) * 16) * 512 + lane * 8;
    #pragma unroll
    for (int j = 0; j < 2; ++j)
        boff[j] = ((nt * 4 + wn * 2 + j) * 16) * 512 + lane * 8;

    f32x4 acc[2][2];
    #pragma unroll
    for (int i = 0; i < 2; ++i)
        #pragma unroll
        for (int j = 0; j < 2; ++j) acc[i][j] = (f32x4){0.f, 0.f, 0.f, 0.f};

    #pragma unroll 2
    for (int kb = 0; kb < 16; ++kb) {
        const int ko = kb * 512;
        s16x8 ah[2], bh[2];
        #pragma unroll
        for (int i = 0; i < 2; ++i)
            ah[i] = *(const s16x8*)(Hh + aoff[i] + ko);
        #pragma unroll
        for (int j = 0; j < 2; ++j)
            bh[j] = *(const s16x8*)(Whi + boff[j] + ko);
        #pragma unroll
        for (int i = 0; i < 2; ++i)
            #pragma unroll
            for (int j = 0; j < 2; ++j)
                acc[i][j] = __builtin_amdgcn_mfma_f32_16x16x32_bf16(ah[i], bh[j], acc[i][j], 0, 0, 0);
    }

    // stage full 64x64 G tile
    #pragma unroll
    for (int i = 0; i < 2; ++i)
        #pragma unroll
        for (int j = 0; j < 2; ++j)
            #pragma unroll
            for (int r = 0; r < 4; ++r)
                Gt[wm * 32 + i * 16 + 4 * q + r][wn * 32 + j * 16 + c] = acc[i][j][r];
    __syncthreads();

    u16* __restrict__ Hhn = Hhi + (size_t)sW * HN;
    u16* __restrict__ Hln = Hlo + (size_t)rw * HN;

    // epilogue: 4 threads per row x 64 rows; each thread 4 units
    const int ug = t & 3;            // 4-unit group within 16-unit tile
    const int ml = t >> 2;           // row 0..63
    const int m  = m0 + ml;
    const float lt = latv[m], ln = lonv[m];
    // units u = nt*16 + ug*4 + j (j<4); fragment offset (derived from fidx):
    const size_t hoff = ((size_t)(m >> 4) * 16 + (nt >> 1)) * 512 +
                        (size_t)((nt & 1) * 2 + (ug >> 1)) * 128 +
                        (m & 15) * 8 + (ug & 1) * 4;
    s16x4 hh4 = *(const s16x4*)(Hh + hoff);
    s16x4 hl4 = *(const s16x4*)(Hl + hoff);
    s16x4 vh, vl;
    #pragma unroll
    for (int j = 0; j < 4; ++j) {
        const float* bb = bias_s[ug * 4 + j];
        f32x4 gv = *(const f32x4*)&Gt[ml][(ug * 4 + j) * 4];
        float r = sigm(gv.x + bb[0] + lt * bb[1] + ln * bb[2]);
        float z = sigm(gv.y + bb[3] + lt * bb[4] + ln * bb[5]);
        float n = tanh_f(fmaf(r, gv.w + bb[9], gv.z + bb[6] + lt * bb[7] + ln * bb[8]));
        float hold = bf2f((u16)hh4[j]) + bf2f((u16)hl4[j]);
        float h = n + z * (hold - n);
        u16 hi = f2bf(h);
        vh[j] = (short)hi;
        vl[j] = (short)f2bf(h - bf2f(hi));
    }
    *(s16x4*)(Hhn + hoff) = vh;
    *(s16x4*)(Hln + hoff) = vl;
}

// ---------------- FAST PATH: batched projection over all steps ----------------
// grid = NS*32: bid>>1 -> (slab, mt), bid&1 -> N half. Single-pass Ahi*Bhi.
__global__ __launch_bounds__(256, 2) void k_proj(
    const u16* __restrict__ Hhi, const u16* __restrict__ Whi,
    const float* __restrict__ b_pr, float* __restrict__ out)
{
    const int bid  = blockIdx.x;
    const int pt   = bid >> 1, ntp = bid & 1;
    const int slab = (pt >> 4) + 1;
    const int mt   = pt & 15;
    const int m0   = mt * 128;
    const int t    = threadIdx.x;
    const int lane = t & 63, wave = t >> 6;
    const int wm   = wave >> 1, wn = wave & 1;
    const int q    = lane >> 4, c = lane & 15;

    __shared__ float Gt[64][132];

    const u16* __restrict__ Hh = Hhi + (size_t)slab * HN;

    int aoff[4], boff[4];
    #pragma unroll
    for (int i = 0; i < 4; ++i) {
        aoff[i] = ((mt * 8 + wm * 4 + i) * 16) * 512 + lane * 8;
        boff[i] = ((128 + ntp * 8 + wn * 4 + i) * 16) * 512 + lane * 8;
    }

    f32x4 acc[4][4];
    #pragma unroll
    for (int i = 0; i < 4; ++i)
        #pragma unroll
        for (int j = 0; j < 4; ++j) acc[i][j] = (f32x4){0.f, 0.f, 0.f, 0.f};

    #pragma unroll 2
    for (int kb = 0; kb < 16; ++kb) {
        const int ko = kb * 512;
        s16x8 ah[4], bh[4];
        #pragma unroll
        for (int i = 0; i < 4; ++i) {
            ah[i] = *(const s16x8*)(Hh  + aoff[i] + ko);
            bh[i] = *(const s16x8*)(Whi + boff[i] + ko);
        }
        #pragma unroll
        for (int i = 0; i < 4; ++i)
            #pragma unroll
            for (int j = 0; j < 4; ++j)
                acc[i][j] = __builtin_amdgcn_mfma_f32_16x16x32_bf16(ah[i], bh[j], acc[i][j], 0, 0, 0);
    }

    for (int half = 0; half < 2; ++half) {
        __syncthreads();
        if (wm == half) {
            #pragma unroll
            for (int i = 0; i < 4; ++i)
                #pragma unroll
                for (int j = 0; j < 4; ++j)
                    #pragma unroll
                    for (int r = 0; r < 4; ++r)
                        Gt[i * 16 + 4 * q + r][wn * 64 + j * 16 + c] = acc[i][j][r];
        }
        __syncthreads();

        const int cl = t & 31, rg = t >> 5;
        const int o  = ntp * 128 + cl * 4;
        const float4 bp = *(const float4*)(b_pr + o);
        float* ob = out + (size_t)slab * B_SZ * LAT + o;
        #pragma unroll
        for (int i = 0; i < 8; ++i) {
            const int ml2 = rg * 8 + i;
            f32x4 g = *(const f32x4*)&Gt[ml2][cl * 4];
            *(float4*)(ob + (size_t)(m0 + half * 64 + ml2) * LAT) =
                make_float4(g.x + bp.x, g.y + bp.y, g.z + bp.z, g.w + bp.w);
        }
    }
}

// ---------------- FALLBACK (R8): fused per-step 128x128 GEMM (3-pass) ----------------
__global__ __launch_bounds__(256) void k_gemm(
    u16* __restrict__ Hhi, u16* __restrict__ Hlo,
    const u16* __restrict__ Whi, const u16* __restrict__ Wlo,
    const float* __restrict__ Bias, const float* __restrict__ b_pr,
    const float* __restrict__ latv, const float* __restrict__ lonv,
    float* __restrict__ out, int s, int ns, int ntb, int ntc)
{
    const int bid  = blockIdx.x;
    const int nt   = ntb + bid % ntc;
    const int mt   = bid / ntc;
    const int m0   = mt * 128, n0 = nt * 128;
    const int t    = threadIdx.x;
    const int lane = t & 63, wave = t >> 6;
    const int wm   = wave >> 1, wn = wave & 1;
    const int q    = lane >> 4, c = lane & 15;

    __shared__ float Gt[64][132];
    __shared__ float bias_s[32][12];
    if (n0 < 2048) {
        for (int i = t; i < 384; i += 256)
            ((float*)bias_s)[i] = Bias[(size_t)(n0 >> 2) * 12 + i];
    }

    const u16* __restrict__ Hh = Hhi + (size_t)((s - 1) & 1) * HN;
    const u16* __restrict__ Hl = Hlo + (size_t)((s - 1) & 1) * HN;

    int aoff[4], boff[4];
    #pragma unroll
    for (int i = 0; i < 4; ++i) {
        aoff[i] = ((mt * 8 + wm * 4 + i) * 16) * 512 + lane * 8;
        boff[i] = ((nt * 8 + wn * 4 + i) * 16) * 512 + lane * 8;
    }

    f32x4 acc[4][4];
    #pragma unroll
    for (int i = 0; i < 4; ++i)
        #pragma unroll
        for (int j = 0; j < 4; ++j) acc[i][j] = (f32x4){0.f, 0.f, 0.f, 0.f};

    #pragma unroll 2
    for (int kb = 0; kb < 16; ++kb) {
        const int ko = kb * 512;
        s16x8 ah[4], al[4], bh[4], bl[4];
        #pragma unroll
        for (int i = 0; i < 4; ++i) {
            ah[i] = *(const s16x8*)(Hh  + aoff[i] + ko);
            al[i] = *(const s16x8*)(Hl  + aoff[i] + ko);
            bh[i] = *(const s16x8*)(Whi + boff[i] + ko);
            bl[i] = *(const s16x8*)(Wlo + boff[i] + ko);
        }
        #pragma unroll
        for (int i = 0; i < 4; ++i)
            #pragma unroll
            for (int j = 0; j < 4; ++j) {
                acc[i][j] = __builtin_amdgcn_mfma_f32_16x16x32_bf16(ah[i], bh[j], acc[i][j], 0, 0, 0);
                acc[i][j] = __builtin_amdgcn_mfma_f32_16x16x32_bf16(al[i], bh[j], acc[i][j], 0, 0, 0);
                acc[i][j] = __builtin_amdgcn_mfma_f32_16x16x32_bf16(ah[i], bl[j], acc[i][j], 0, 0, 0);
            }
    }

    u16* __restrict__ Hhn = Hhi + (size_t)(s & 1) * HN;
    u16* __restrict__ Hln = Hlo + (size_t)(s & 1) * HN;
    const int u0t = n0 >> 2;

    for (int half = 0; half < 2; ++half) {
        __syncthreads();
        if (wm == half) {
            #pragma unroll
            for (int i = 0; i < 4; ++i)
                #pragma unroll
                for (int j = 0; j < 4; ++j)
                    #pragma unroll
                    for (int r = 0; r < 4; ++r)
                        Gt[i * 16 + 4 * q + r][wn * 64 + j * 16 + c] = acc[i][j][r];
        }
        __syncthreads();

        if (n0 < 2048) {
            const int uo = t & 3;
            const int ml = t >> 2;
            const int m  = m0 + half * 64 + ml;
            const float lt = latv[m], ln = lonv[m];
            const size_t hoff = ((size_t)(m >> 4) * 16 + (u0t >> 5)) * 512 +
                                (size_t)uo * 128 + (m & 15) * 8;
            s16x8 hh8 = *(const s16x8*)(Hh + hoff);
            s16x8 hl8 = *(const s16x8*)(Hl + hoff);
            s16x8 vh, vl;
            #pragma unroll
            for (int j = 0; j < 8; ++j) {
                const float* bb = bias_s[uo * 8 + j];
                f32x4 gv = *(const f32x4*)&Gt[ml][(uo * 8 + j) * 4];
                float r = sigm(gv.x + bb[0] + lt * bb[1] + ln * bb[2]);
                float z = sigm(gv.y + bb[3] + lt * bb[4] + ln * bb[5]);
                float n = tanh_f(fmaf(r, gv.w + bb[9], gv.z + bb[6] + lt * bb[7] + ln * bb[8]));
                float hold = bf2f((u16)hh8[j]) + bf2f((u16)hl8[j]);
                float h = n + z * (hold - n);
                u16 hi = f2bf(h);
                vh[j] = (short)hi;
                vl[j] = (short)f2bf(h - bf2f(hi));
            }
            *(s16x8*)(Hhn + hoff) = vh;
            *(s16x8*)(Hln + hoff) = vl;
        } else {
            const int cl = t & 31, rg = t >> 5;
            const int o  = (n0 - 2048) + cl * 4;
            const float4 bp = *(const float4*)(b_pr + o);
            float* ob = out + (size_t)(s - 1) * B_SZ * LAT + o;
            #pragma unroll
            for (int i = 0; i < 8; ++i) {
                const int ml = rg * 8 + i;
                f32x4 g = *(const f32x4*)&Gt[ml][cl * 4];
                *(float4*)(ob + (size_t)(m0 + half * 64 + ml) * LAT) =
                    make_float4(g.x + bp.x, g.y + bp.y, g.z + bp.z, g.w + bp.w);
            }
        }
    }
}

extern "C" void kernel_launch(void* const* d_in, const int* in_sizes, int n_in,
                              void* d_out, int out_size, void* d_ws, size_t ws_size,
                              hipStream_t stream)
{
    const float* p0   = (const float*)d_in[0];
    const float* latv = (const float*)d_in[1];
    const float* lonv = (const float*)d_in[2];
    const float* W_ih = (const float*)d_in[3];
    const float* W_hh = (const float*)d_in[4];
    const float* b_ih = (const float*)d_in[5];
    const float* b_hh = (const float*)d_in[6];
    const float* W_pr = (const float*)d_in[7];
    const float* b_pr = (const float*)d_in[8];
    float* out = (float*)d_out;

    const int NS = out_size / (B_SZ * LAT) - 1;   // 100

    // layout: gi1T | Bias | Hhi[nslab] | Hlo[2]; Whi/Wlo alias gi1T (dead after k_h1)
    float* gi1T = (float*)d_ws;
    float* Bias = gi1T + 3 * HID * B_SZ;
    u16*   Whi  = (u16*)gi1T;
    u16*   Wlo  = Whi + (size_t)NROW * HID;

    const size_t offH     = ((size_t)3 * HID * B_SZ + 512 * 12) * sizeof(float);
    const size_t slabB    = (size_t)HN * sizeof(u16);
    const size_t needFast = offH + (size_t)(NS + 1) * slabB + 2 * slabB;
    const bool   fast     = ws_size >= needFast;
    const int    nslabHi  = fast ? (NS + 1) : 2;

    u16* Hhi = (u16*)((char*)d_ws + offH);
    u16* Hlo = Hhi + (size_t)nslabHi * HN;

    hipLaunchKernelGGL(k_bias,   dim3(HID),  dim3(64),  0, stream, W_ih, b_ih, b_hh, b_pr, Bias);
    hipLaunchKernelGGL(k_gi1,    dim3(256),  dim3(512), 0, stream, p0, latv, lonv, W_ih, b_ih, gi1T, out);
    hipLaunchKernelGGL(k_h1,     dim3(4096), dim3(256), 0, stream, gi1T, Bias, Hhi, Hlo);
    hipLaunchKernelGGL(k_wsplit, dim3(NROW), dim3(512), 0, stream, W_ih, W_hh, W_pr, Whi, Wlo);

    if (fast) {
        for (int s = 2; s <= NS; ++s) {
            hipLaunchKernelGGL(k_gates, dim3(1024), dim3(256), 0, stream,
                               Hhi, Hlo, Whi, Bias, latv, lonv,
                               s - 1, s, (s - 1) & 1, s & 1);
        }
        hipLaunchKernelGGL(k_proj, dim3(NS * 32), dim3(256), 0, stream,
                           Hhi, Whi, b_pr, out);
    } else {
        for (int s = 2; s <= NS + 1; ++s) {
            const int ntc = (s <= NS) ? 18 : 2;
            const int ntb = (s <= NS) ? 0 : 16;
            hipLaunchKernelGGL(k_gemm, dim3(16 * ntc), dim3(256), 0, stream,
                               Hhi, Hlo, Whi, Wlo, Bias, b_pr, latv, lonv, out, s, NS, ntb, ntc);
        }
    }
}